// Round 12
// baseline (9603.254 us; speedup 1.0000x reference)
//
#include <hip/hip_runtime.h>
#include <hip/hip_fp16.h>

#define T_STEPS 2048
#define BATCH   32
#define DIM     1024
#define NWG     32      // rec workgroups; wg owns 32 output cols
#define WCOLS   32

typedef _Float16 half2_t __attribute__((ext_vector_type(2)));
typedef _Float16 f16x4 __attribute__((ext_vector_type(4)));
typedef _Float16 f16x8 __attribute__((ext_vector_type(8)));
typedef float    f32x4 __attribute__((ext_vector_type(4)));

#define TAG_MASK 0x00010001u   // bit0 = f16[0].lsb, bit16 = f16[1].lsb

__device__ __forceinline__ f16x8 cvt8(f32x4 a, f32x4 b) {
    f16x8 r;
    r[0]=(_Float16)a[0]; r[1]=(_Float16)a[1]; r[2]=(_Float16)a[2]; r[3]=(_Float16)a[3];
    r[4]=(_Float16)b[0]; r[5]=(_Float16)b[1]; r[6]=(_Float16)b[2]; r[7]=(_Float16)b[3];
    return r;
}

// ---------------------------------------------------------------------------
// init kernels (run every launch; replays don't re-poison d_ws):
// zero reader-done flags; scrub ring to tag=3 (never produced: live tags are
// (t+1)%3 in {0,1,2}) — kills cross-replay staleness.
// ---------------------------------------------------------------------------
__global__ void flag_init(int* __restrict__ f) { f[threadIdx.x] = 0; }

__global__ void ring_scrub(uint2* __restrict__ ring) {
    const int i = blockIdx.x * blockDim.x + threadIdx.x;   // 16384 x 8B
    ring[i] = uint2{TAG_MASK, TAG_MASK};
}

// ---------------------------------------------------------------------------
// repack W_h (fp32 [k][n]) -> f16, B-fragment-swizzled blocks:
// P[n][pos][e], blk=k>>3, e=k&7, pos = blk ^ (n&7)
// ---------------------------------------------------------------------------
__global__ void conv_pack(const float* __restrict__ Wh, _Float16* __restrict__ P) {
    const int idx = blockIdx.x * blockDim.x + threadIdx.x;  // DIM*DIM
    const int k = idx >> 10, n = idx & (DIM - 1);
    const int pos = (k >> 3) ^ (n & 7);
    P[(size_t)n * 1024 + pos * 8 + (k & 7)] = (_Float16)Wh[idx];
}

// ---------------------------------------------------------------------------
// xW = x @ W_x + b  (validated rounds 1-11, unchanged) -> h_all[1:]
// ---------------------------------------------------------------------------
#define BM 128
#define BN 128
#define BK 32
#define LDT 40

__global__ __launch_bounds__(256) void gemm_xw(
    const float* __restrict__ X, const float* __restrict__ Wx,
    const float* __restrict__ bias, float* __restrict__ out)
{
    __shared__ _Float16 As[BM][LDT];
    __shared__ _Float16 Bs[BN][LDT];

    const int tid = threadIdx.x;
    const int m0 = blockIdx.x * BM, n0 = blockIdx.y * BN;
    const int lane = tid & 63, wid = tid >> 6;
    const int wm = (wid >> 1) * 64, wn = (wid & 1) * 64;
    const int lr = lane & 15, lk = (lane >> 4) * 8;
    const int ar = tid >> 1, ac = (tid & 1) * 16;
    const int bk = tid >> 3, bn = (tid & 7) * 16;

    f32x4 acc[4][4] = {};

    for (int k0 = 0; k0 < DIM; k0 += BK) {
        __syncthreads();
        {
            const float* src = X + (size_t)(m0 + ar) * DIM + k0 + ac;
            float4 q0 = *(const float4*)(src + 0);
            float4 q1 = *(const float4*)(src + 4);
            float4 q2 = *(const float4*)(src + 8);
            float4 q3 = *(const float4*)(src + 12);
            f16x8 p0, p1;
            p0[0]=(_Float16)q0.x; p0[1]=(_Float16)q0.y; p0[2]=(_Float16)q0.z; p0[3]=(_Float16)q0.w;
            p0[4]=(_Float16)q1.x; p0[5]=(_Float16)q1.y; p0[6]=(_Float16)q1.z; p0[7]=(_Float16)q1.w;
            p1[0]=(_Float16)q2.x; p1[1]=(_Float16)q2.y; p1[2]=(_Float16)q2.z; p1[3]=(_Float16)q2.w;
            p1[4]=(_Float16)q3.x; p1[5]=(_Float16)q3.y; p1[6]=(_Float16)q3.z; p1[7]=(_Float16)q3.w;
            *(f16x8*)&As[ar][ac] = p0;
            *(f16x8*)&As[ar][ac + 8] = p1;
        }
        {
            const float* src = Wx + (size_t)(k0 + bk) * DIM + n0 + bn;
            float4 q0 = *(const float4*)(src + 0);
            float4 q1 = *(const float4*)(src + 4);
            float4 q2 = *(const float4*)(src + 8);
            float4 q3 = *(const float4*)(src + 12);
            float vv[16];
            *(float4*)&vv[0] = q0; *(float4*)&vv[4] = q1;
            *(float4*)&vv[8] = q2; *(float4*)&vv[12] = q3;
            #pragma unroll
            for (int i = 0; i < 16; ++i) Bs[bn + i][bk] = (_Float16)vv[i];
        }
        __syncthreads();
        f16x8 a[4], bb[4];
        #pragma unroll
        for (int f = 0; f < 4; ++f) a[f]  = *(const f16x8*)&As[wm + f * 16 + lr][lk];
        #pragma unroll
        for (int f = 0; f < 4; ++f) bb[f] = *(const f16x8*)&Bs[wn + f * 16 + lr][lk];
        #pragma unroll
        for (int i = 0; i < 4; ++i)
            #pragma unroll
            for (int j = 0; j < 4; ++j)
                acc[i][j] = __builtin_amdgcn_mfma_f32_16x16x32_f16(a[i], bb[j], acc[i][j], 0, 0, 0);
    }

    #pragma unroll
    for (int i = 0; i < 4; ++i)
        #pragma unroll
        for (int j = 0; j < 4; ++j) {
            const int col = n0 + wn + j * 16 + lr;
            const float bv = bias[col];
            #pragma unroll
            for (int r = 0; r < 4; ++r) {
                const int row = m0 + wm + i * 16 + (lane >> 4) * 4 + r;
                __builtin_nontemporal_store(acc[i][j][r] + bv, out + (size_t)row * DIM + col);
            }
        }
}

// ---------------------------------------------------------------------------
// recurrence: 32 wgs x 256 thr. Tagged self-validating exchange:
//   publish h_{t+1} f16 with 2-bit tag ((t+1)%3) in LSBs of f16[0]/f16[1]
//   per 8B unit (sc1, NO drain/flag/barrier) -> issue 16 reloads -> spin
//   {vmcnt(0); check per-line tags; reissue missing}. One barrier/step.
// Outputs (hs, h_all) NONTEMPORAL (R11's plain hs stores polluted L3 and
// evicted the ring -> HBM spin storm) and issued AFTER the spin so their
// acks never sit inside a vmcnt(0); they drain under next step's MFMA.
// Ring depth-2 safety: lazy reader-done flags (posted post-reload, checked
// by wave 0 pre-barrier-A two steps stale). Tag mod 3 vs ring mod 2: stale
// distances 2/4 never match; scrub tag 3 kills cross-replay residue.
// ---------------------------------------------------------------------------
__global__ __launch_bounds__(256, 1) void elman_rec(
    const float* __restrict__ h0, const _Float16* __restrict__ P,
    float* __restrict__ hs, float* __restrict__ h_all,
    int* __restrict__ rdone, _Float16* __restrict__ xchg)
{
    __shared__ _Float16 Hs[32 * 128 * 8];      // [row][pos][8]  64 KB
    __shared__ _Float16 Ws[32 * 128 * 8];      // [colL][pos][8] 64 KB
    __shared__ _Float16 ht2h[2 * 4 * 32 * 36]; // f16 K-partials, dbuf, 18 KB

    const int wg  = blockIdx.x;
    const int tid = threadIdx.x;
    const int w = tid >> 6, lane = tid & 63, lr = lane & 15, kg = lane >> 4;
    const int wcol0 = wg * WCOLS;

    // ---- stage W slice (swizzle pre-baked by conv_pack)
    {
        const uint4* src = (const uint4*)(P + (size_t)wcol0 * 1024);
        uint4* dst = (uint4*)Ws;
        #pragma unroll
        for (int j = 0; j < 16; ++j) dst[tid + 256 * j] = src[tid + 256 * j];
    }
    // ---- stage h0 -> Hs; wg0 writes h_all[0] = h0
    #pragma unroll
    for (int j = 0; j < 16; ++j) {
        const int bi = tid + 256 * j;
        const int r = bi >> 7, blk = bi & 127;
        f32x4 q0 = *(const f32x4*)(h0 + (size_t)r * DIM + blk * 8);
        f32x4 q1 = *(const f32x4*)(h0 + (size_t)r * DIM + blk * 8 + 4);
        *(f16x8*)&Hs[((r << 7) + (blk ^ (r & 7))) * 8] = cvt8(q0, q1);
        if (wg == 0) {
            *(f32x4*)(h_all + (size_t)r * DIM + blk * 8)     = q0;
            *(f32x4*)(h_all + (size_t)r * DIM + blk * 8 + 4) = q1;
        }
    }
    __syncthreads();

    const int er = tid >> 3, ec4 = (tid & 7) * 4;   // emit coords
    const int rl_rh = lane >> 5;                    // reload: row parity
    const int rl_blk = 32 * w + (lane & 31);        // reload: 8-f16 block index
    const int cw = wg >> 3;       // which consumer WAVE reads my wg's cols

    int tag = 1;                  // (t+1) % 3

    for (int t = 0; t < T_STEPS; ++t) {
        float* slot = h_all + (size_t)(t + 1) * (BATCH * DIM);
        f32x4 xw = *(const f32x4*)(slot + (size_t)er * DIM + wcol0 + ec4);

        // ---- MFMA, K-split: wave w covers k-blocks [32w, 32w+32)
        f32x4 a00 = {0,0,0,0}, a01 = {0,0,0,0}, a10 = {0,0,0,0}, a11 = {0,0,0,0};
        #pragma unroll
        for (int q = 0; q < 8; ++q) {
            const int blk = (w * 8 + q) * 4 + kg;
            const int pa = blk ^ (lr & 7);
            f16x8 A0 = *(const f16x8*)&Hs[((lr << 7) + pa) * 8];
            f16x8 A1 = *(const f16x8*)&Hs[(((16 + lr) << 7) + pa) * 8];
            f16x8 B0 = *(const f16x8*)&Ws[((lr << 7) + pa) * 8];
            f16x8 B1 = *(const f16x8*)&Ws[(((16 + lr) << 7) + pa) * 8];
            a00 = __builtin_amdgcn_mfma_f32_16x16x32_f16(A0, B0, a00, 0, 0, 0);
            a01 = __builtin_amdgcn_mfma_f32_16x16x32_f16(A0, B1, a01, 0, 0, 0);
            a10 = __builtin_amdgcn_mfma_f32_16x16x32_f16(A1, B0, a10, 0, 0, 0);
            a11 = __builtin_amdgcn_mfma_f32_16x16x32_f16(A1, B1, a11, 0, 0, 0);
        }
        {
            _Float16* hb = ht2h + (size_t)(t & 1) * (4 * 32 * 36) + (size_t)w * (32 * 36);
            #pragma unroll
            for (int r = 0; r < 4; ++r) {
                hb[(kg * 4 + r) * 36 + lr]           = (_Float16)a00[r];
                hb[(kg * 4 + r) * 36 + 16 + lr]      = (_Float16)a01[r];
                hb[(16 + kg * 4 + r) * 36 + lr]      = (_Float16)a10[r];
                hb[(16 + kg * 4 + r) * 36 + 16 + lr] = (_Float16)a11[r];
            }
        }

        // ---- ring write-safety: wave 0 checks the 32 reader-done flags of
        // MY cols (read by wave cw of every wg) are >= t-1 (2-step slack;
        // first poll passes unless a reader lags).
        if (w == 0 && lane < 32 && t >= 2) {
            const int* fp = rdone + ((lane * 4 + cw) * 4);
            int g = 0, v;
            do {
                v = __hip_atomic_load(fp, __ATOMIC_RELAXED, __HIP_MEMORY_SCOPE_AGENT);
            } while (v < t - 1 && ++g < (1 << 20));
        }
        __syncthreads();   // barrier A: partials visible; publish gate passed

        // ---- emit: reduce partials, +xW, tanh
        f32x4 z = xw;
        {
            const _Float16* hb = ht2h + (size_t)(t & 1) * (4 * 32 * 36);
            #pragma unroll
            for (int ww = 0; ww < 4; ++ww) {
                f16x4 pv = *(const f16x4*)&hb[(ww * 32 + er) * 36 + ec4];
                z[0] += (float)pv[0]; z[1] += (float)pv[1];
                z[2] += (float)pv[2]; z[3] += (float)pv[3];
            }
        }
        f32x4 h;
        #pragma unroll
        for (int i = 0; i < 4; ++i) {
            const float e = __expf(2.0f * z[i]);
            h[i] = 1.0f - 2.0f / (e + 1.0f);
        }

        if (t == T_STEPS - 1) {   // last step: outputs only
            __builtin_nontemporal_store(h, (f32x4*)(hs + (size_t)t * (BATCH * DIM)
                                                    + (size_t)er * DIM + wcol0 + ec4));
            __builtin_nontemporal_store(h, (f32x4*)(slot + (size_t)er * DIM + wcol0 + ec4));
            break;
        }

        const unsigned exp_pat = (unsigned)(tag & 1) | ((unsigned)(tag >> 1) << 16);

        // ---- publish tagged f16 (8 B/thread, sc1); ack overlaps the reloads
        {
            half2_t lo, hi;
            lo[0] = (_Float16)h[0]; lo[1] = (_Float16)h[1];
            hi[0] = (_Float16)h[2]; hi[1] = (_Float16)h[3];
            uint2 pk;
            pk.x = (__builtin_bit_cast(unsigned, lo) & ~TAG_MASK) | exp_pat;
            pk.y = __builtin_bit_cast(unsigned, hi);
            _Float16* xp = xchg + (size_t)((t + 1) & 1) * (BATCH * DIM)
                         + (size_t)er * DIM + wcol0 + ec4;
            asm volatile("global_store_dwordx2 %0, %1, off sc1"
                         :: "v"(xp), "v"(pk) : "memory");
        }

        // ---- reload own k-slice: issue 16, then spin on per-line tags
        const _Float16* xb = xchg + (size_t)((t + 1) & 1) * (BATCH * DIM);
        uint4 q[16];
        #pragma unroll
        for (int i = 0; i < 16; ++i) {
            const int row = 2 * i + rl_rh;
            const _Float16* ap = xb + (size_t)row * DIM + rl_blk * 8;
            asm volatile("global_load_dwordx4 %0, %1, off sc1"
                         : "=v"(q[i]) : "v"(ap) : "memory");
        }
        unsigned need = 0xFFFFu;
        int g = 0;
        do {
            asm volatile("s_waitcnt vmcnt(0)" ::: "memory");
            __builtin_amdgcn_sched_barrier(0);
            #pragma unroll
            for (int i = 0; i < 16; ++i) {
                if (need & (1u << i)) {
                    const unsigned bad = ((q[i].x ^ exp_pat) | (q[i].z ^ exp_pat)) & TAG_MASK;
                    if (bad == 0) need &= ~(1u << i);
                }
            }
            if (!need) break;
            #pragma unroll
            for (int i = 0; i < 16; ++i) {
                if (need & (1u << i)) {
                    const int row = 2 * i + rl_rh;
                    const _Float16* ap = xb + (size_t)row * DIM + rl_blk * 8;
                    asm volatile("global_load_dwordx4 %0, %1, off sc1"
                                 : "=v"(q[i]) : "v"(ap) : "memory");
                }
            }
        } while (++g < (1 << 20));
        __builtin_amdgcn_sched_barrier(0);
        #pragma unroll
        for (int i = 0; i < 16; ++i) {
            const int row = 2 * i + rl_rh;
            *(uint4*)&Hs[((row << 7) + (rl_blk ^ (row & 7))) * 8] = q[i];
        }

        // ---- post reader-done (lazy; 2-step slack, no drain needed)
        if (lane == 0)
            __hip_atomic_store(rdone + ((wg * 4 + w) * 4), t + 1,
                               __ATOMIC_RELAXED, __HIP_MEMORY_SCOPE_AGENT);

        // ---- outputs LAST, nontemporal: acks drain under next step's MFMA
        __builtin_nontemporal_store(h, (f32x4*)(hs + (size_t)t * (BATCH * DIM)
                                                + (size_t)er * DIM + wcol0 + ec4));
        __builtin_nontemporal_store(h, (f32x4*)(slot + (size_t)er * DIM + wcol0 + ec4));

        tag = (tag == 2) ? 0 : tag + 1;
        // no barrier: next MFMA reads only this wave's own k-blocks
    }
}

extern "C" void kernel_launch(void* const* d_in, const int* in_sizes, int n_in,
                              void* d_out, int out_size, void* d_ws, size_t ws_size,
                              hipStream_t stream) {
    const float* x    = (const float*)d_in[0];   // [T][B][D]
    const float* h0   = (const float*)d_in[1];   // [B][D]
    const float* Wx   = (const float*)d_in[2];   // [D][D]
    const float* Wh   = (const float*)d_in[3];   // [D][D]
    const float* bias = (const float*)d_in[4];   // [D]

    float* hs    = (float*)d_out;
    float* h_all = hs + (size_t)T_STEPS * BATCH * DIM;

    int*       rdone = (int*)d_ws;                              // 512 ints (per wg,wave, 16B apart)
    _Float16*  xchg  = (_Float16*)((char*)d_ws + 4096);         // 128 KB ring (2 slots)
    _Float16*  P     = (_Float16*)((char*)d_ws + 4096 + 131072);// 2 MB packed W_h

    flag_init<<<1, 1024, 0, stream>>>((int*)d_ws);
    ring_scrub<<<64, 256, 0, stream>>>((uint2*)xchg);
    conv_pack<<<(DIM * DIM) / 256, 256, 0, stream>>>(Wh, P);

    dim3 g((T_STEPS * BATCH) / BM, DIM / BN);
    gemm_xw<<<g, 256, 0, stream>>>(x, Wx, bias, h_all + (size_t)BATCH * DIM);

    elman_rec<<<NWG, 256, 0, stream>>>(h0, P, hs, h_all, rdone, xchg);
}

// Round 14
// 7482.546 us; speedup vs baseline: 1.2834x; 1.2834x over previous
//
#include <hip/hip_runtime.h>
#include <hip/hip_fp16.h>

#define T_STEPS 2048
#define BATCH   32
#define DIM     1024
#define NWG     32      // rec workgroups; wg owns 32 output cols
#define WCOLS   32

typedef _Float16 half2_t __attribute__((ext_vector_type(2)));
typedef _Float16 f16x8 __attribute__((ext_vector_type(8)));
typedef float    f32x4 __attribute__((ext_vector_type(4)));

__device__ __forceinline__ f16x8 cvt8(f32x4 a, f32x4 b) {
    f16x8 r;
    r[0]=(_Float16)a[0]; r[1]=(_Float16)a[1]; r[2]=(_Float16)a[2]; r[3]=(_Float16)a[3];
    r[4]=(_Float16)b[0]; r[5]=(_Float16)b[1]; r[6]=(_Float16)b[2]; r[7]=(_Float16)b[3];
    return r;
}

// ---------------------------------------------------------------------------
// zero flags every launch (graph replays don't re-poison d_ws)
// ---------------------------------------------------------------------------
__global__ void flag_init(int* __restrict__ f) { f[threadIdx.x] = 0; }

// ---------------------------------------------------------------------------
// repack W_h (fp32 [k][n]) -> f16, B-fragment-swizzled blocks:
// P[n][pos][e], blk=k>>3, e=k&7, pos = blk ^ (n&7)
// ---------------------------------------------------------------------------
__global__ void conv_pack(const float* __restrict__ Wh, _Float16* __restrict__ P) {
    const int idx = blockIdx.x * blockDim.x + threadIdx.x;  // DIM*DIM
    const int k = idx >> 10, n = idx & (DIM - 1);
    const int pos = (k >> 3) ^ (n & 7);
    P[(size_t)n * 1024 + pos * 8 + (k & 7)] = (_Float16)Wh[idx];
}

// ---------------------------------------------------------------------------
// xW = x @ W_x + b  (validated rounds 1-13, unchanged) -> h_all[1:]
// ---------------------------------------------------------------------------
#define BM 128
#define BN 128
#define BK 32
#define LDT 40

__global__ __launch_bounds__(256) void gemm_xw(
    const float* __restrict__ X, const float* __restrict__ Wx,
    const float* __restrict__ bias, float* __restrict__ out)
{
    __shared__ _Float16 As[BM][LDT];
    __shared__ _Float16 Bs[BN][LDT];

    const int tid = threadIdx.x;
    const int m0 = blockIdx.x * BM, n0 = blockIdx.y * BN;
    const int lane = tid & 63, wid = tid >> 6;
    const int wm = (wid >> 1) * 64, wn = (wid & 1) * 64;
    const int lr = lane & 15, lk = (lane >> 4) * 8;
    const int ar = tid >> 1, ac = (tid & 1) * 16;
    const int bk = tid >> 3, bn = (tid & 7) * 16;

    f32x4 acc[4][4] = {};

    for (int k0 = 0; k0 < DIM; k0 += BK) {
        __syncthreads();
        {
            const float* src = X + (size_t)(m0 + ar) * DIM + k0 + ac;
            float4 q0 = *(const float4*)(src + 0);
            float4 q1 = *(const float4*)(src + 4);
            float4 q2 = *(const float4*)(src + 8);
            float4 q3 = *(const float4*)(src + 12);
            f16x8 p0, p1;
            p0[0]=(_Float16)q0.x; p0[1]=(_Float16)q0.y; p0[2]=(_Float16)q0.z; p0[3]=(_Float16)q0.w;
            p0[4]=(_Float16)q1.x; p0[5]=(_Float16)q1.y; p0[6]=(_Float16)q1.z; p0[7]=(_Float16)q1.w;
            p1[0]=(_Float16)q2.x; p1[1]=(_Float16)q2.y; p1[2]=(_Float16)q2.z; p1[3]=(_Float16)q2.w;
            p1[4]=(_Float16)q3.x; p1[5]=(_Float16)q3.y; p1[6]=(_Float16)q3.z; p1[7]=(_Float16)q3.w;
            *(f16x8*)&As[ar][ac] = p0;
            *(f16x8*)&As[ar][ac + 8] = p1;
        }
        {
            const float* src = Wx + (size_t)(k0 + bk) * DIM + n0 + bn;
            float4 q0 = *(const float4*)(src + 0);
            float4 q1 = *(const float4*)(src + 4);
            float4 q2 = *(const float4*)(src + 8);
            float4 q3 = *(const float4*)(src + 12);
            float vv[16];
            *(float4*)&vv[0] = q0; *(float4*)&vv[4] = q1;
            *(float4*)&vv[8] = q2; *(float4*)&vv[12] = q3;
            #pragma unroll
            for (int i = 0; i < 16; ++i) Bs[bn + i][bk] = (_Float16)vv[i];
        }
        __syncthreads();
        f16x8 a[4], bb[4];
        #pragma unroll
        for (int f = 0; f < 4; ++f) a[f]  = *(const f16x8*)&As[wm + f * 16 + lr][lk];
        #pragma unroll
        for (int f = 0; f < 4; ++f) bb[f] = *(const f16x8*)&Bs[wn + f * 16 + lr][lk];
        #pragma unroll
        for (int i = 0; i < 4; ++i)
            #pragma unroll
            for (int j = 0; j < 4; ++j)
                acc[i][j] = __builtin_amdgcn_mfma_f32_16x16x32_f16(a[i], bb[j], acc[i][j], 0, 0, 0);
    }

    #pragma unroll
    for (int i = 0; i < 4; ++i)
        #pragma unroll
        for (int j = 0; j < 4; ++j) {
            const int col = n0 + wn + j * 16 + lr;
            const float bv = bias[col];
            #pragma unroll
            for (int r = 0; r < 4; ++r) {
                const int row = m0 + wm + i * 16 + (lane >> 4) * 4 + r;
                __builtin_nontemporal_store(acc[i][j][r] + bv, out + (size_t)row * DIM + col);
            }
        }
}

// ---------------------------------------------------------------------------
// recurrence: 32 wgs x 256 thr. R8-validated protocol with ONE change:
// outputs (hs nontemporal, h_all plain) are issued AFTER the 16 reload loads
// and excluded from every critical drain — the publish vmcnt(0) no longer
// waits the ~0.9us HBM ack of the hs store (R8 drained publish+hs+h_all
// together). vmcnt(2) after the outputs waits exactly the 16 oldest ops
// (the reloads); the 2 output stores retire in background during the next
// MFMA phase, long before the next publish drain.
// Per step: MFMA (K-split over 4 waves) -> f32 partials -> barrier A ->
// emit tanh -> publish f16 8B sc1 -> vmcnt(0) [publish only] -> barrier B ->
// wg flag (agent atomic) -> per-wave poll of its 8 k-slice producers ->
// 16 sc1 reloads -> outputs -> vmcnt(2) -> Hs LDS writes.
// Ht2 single-buffer safety: barrier B separates emit reads (iter t) from the
// next iteration's Ht2 writes. Ring depth 2: flag t+1 implies barrier B of
// step t passed, i.e. all waves' step t-1 reloads retired.
// ---------------------------------------------------------------------------
__global__ __launch_bounds__(256, 1) void elman_rec(
    const float* __restrict__ h0, const _Float16* __restrict__ P,
    float* __restrict__ hs, float* __restrict__ h_all,
    int* __restrict__ flags, _Float16* __restrict__ xchg)
{
    __shared__ _Float16 Hs[32 * 128 * 8];   // [row][pos][8]  64 KB
    __shared__ _Float16 Ws[32 * 128 * 8];   // [colL][pos][8] 64 KB
    __shared__ float    Ht2[4][32][36];     // K-split partials, 18 KB

    const int wg  = blockIdx.x;
    const int tid = threadIdx.x;
    const int w = tid >> 6, lane = tid & 63, lr = lane & 15, kg = lane >> 4;
    const int wcol0 = wg * WCOLS;

    // ---- stage W slice (swizzle pre-baked by conv_pack)
    {
        const uint4* src = (const uint4*)(P + (size_t)wcol0 * 1024);
        uint4* dst = (uint4*)Ws;
        #pragma unroll
        for (int j = 0; j < 16; ++j) dst[tid + 256 * j] = src[tid + 256 * j];
    }
    // ---- stage h0 -> Hs; wg0 writes h_all[0] = h0
    #pragma unroll
    for (int j = 0; j < 16; ++j) {
        const int bi = tid + 256 * j;
        const int r = bi >> 7, blk = bi & 127;
        f32x4 q0 = *(const f32x4*)(h0 + (size_t)r * DIM + blk * 8);
        f32x4 q1 = *(const f32x4*)(h0 + (size_t)r * DIM + blk * 8 + 4);
        *(f16x8*)&Hs[((r << 7) + (blk ^ (r & 7))) * 8] = cvt8(q0, q1);
        if (wg == 0) {
            *(f32x4*)(h_all + (size_t)r * DIM + blk * 8)     = q0;
            *(f32x4*)(h_all + (size_t)r * DIM + blk * 8 + 4) = q1;
        }
    }
    __syncthreads();

    const int er = tid >> 3, ec4 = (tid & 7) * 4;   // emit coords
    const int rl_rh = lane >> 5;                    // reload: row parity
    const int rl_blk = 32 * w + (lane & 31);        // reload: 8-f16 block index

    for (int t = 0; t < T_STEPS; ++t) {
        float* slot = h_all + (size_t)(t + 1) * (BATCH * DIM);

        // xW for emit (plain load; hidden under MFMA)
        f32x4 xw = *(const f32x4*)(slot + (size_t)er * DIM + wcol0 + ec4);

        // ---- MFMA, K-split: wave w covers k-blocks [32w, 32w+32)
        f32x4 a00 = {0,0,0,0}, a01 = {0,0,0,0}, a10 = {0,0,0,0}, a11 = {0,0,0,0};
        #pragma unroll
        for (int q = 0; q < 8; ++q) {
            const int blk = (w * 8 + q) * 4 + kg;
            const int pa = blk ^ (lr & 7);
            f16x8 A0 = *(const f16x8*)&Hs[((lr << 7) + pa) * 8];
            f16x8 A1 = *(const f16x8*)&Hs[(((16 + lr) << 7) + pa) * 8];
            f16x8 B0 = *(const f16x8*)&Ws[((lr << 7) + pa) * 8];
            f16x8 B1 = *(const f16x8*)&Ws[(((16 + lr) << 7) + pa) * 8];
            a00 = __builtin_amdgcn_mfma_f32_16x16x32_f16(A0, B0, a00, 0, 0, 0);
            a01 = __builtin_amdgcn_mfma_f32_16x16x32_f16(A0, B1, a01, 0, 0, 0);
            a10 = __builtin_amdgcn_mfma_f32_16x16x32_f16(A1, B0, a10, 0, 0, 0);
            a11 = __builtin_amdgcn_mfma_f32_16x16x32_f16(A1, B1, a11, 0, 0, 0);
        }
        #pragma unroll
        for (int r = 0; r < 4; ++r) {
            Ht2[w][kg * 4 + r]      [lr]      = a00[r];
            Ht2[w][kg * 4 + r]      [16 + lr] = a01[r];
            Ht2[w][16 + kg * 4 + r] [lr]      = a10[r];
            Ht2[w][16 + kg * 4 + r] [16 + lr] = a11[r];
        }
        __syncthreads();   // barrier A: partials visible

        // ---- emit: reduce partials, +xW, tanh
        f32x4 z = xw;
        #pragma unroll
        for (int ww = 0; ww < 4; ++ww) z += *(const f32x4*)&Ht2[ww][er][ec4];
        f32x4 h;
        #pragma unroll
        for (int i = 0; i < 4; ++i) {
            const float e = __expf(2.0f * z[i]);
            h[i] = 1.0f - 2.0f / (e + 1.0f);
        }

        if (t == T_STEPS - 1) {   // last step: outputs only
            __builtin_nontemporal_store(h, (f32x4*)(hs + (size_t)t * (BATCH * DIM)
                                                    + (size_t)er * DIM + wcol0 + ec4));
            *(f32x4*)(slot + (size_t)er * DIM + wcol0 + ec4) = h;
            break;
        }

        // ---- publish f16 (8 B/thread, sc1); the ONLY store on the drain path
        {
            half2_t lo, hi;
            lo[0] = (_Float16)h[0]; lo[1] = (_Float16)h[1];
            hi[0] = (_Float16)h[2]; hi[1] = (_Float16)h[3];
            uint2 pk;
            pk.x = __builtin_bit_cast(unsigned, lo);
            pk.y = __builtin_bit_cast(unsigned, hi);
            _Float16* xp = xchg + (size_t)((t + 1) & 1) * (BATCH * DIM)
                         + (size_t)er * DIM + wcol0 + ec4;
            asm volatile("global_store_dwordx2 %0, %1, off sc1"
                         :: "v"(xp), "v"(pk) : "memory");
        }
        // explicit drain: inline-asm stores are NOT covered by the barrier's
        // compiler waitcnt (round-7 race). Publish only — outputs of the
        // previous iteration retired during the MFMA phase above.
        asm volatile("s_waitcnt vmcnt(0)" ::: "memory");
        __syncthreads();   // barrier B (also guards Ht2 single-buffer reuse)
        if (tid == 0)
            __hip_atomic_store(flags + wg * 16, t + 1, __ATOMIC_RELAXED,
                               __HIP_MEMORY_SCOPE_AGENT);

        // ---- per-wave poll: the 8 producers of this wave's k-slice
        if (lane < 8) {
            const int* fp = flags + (w * 8 + lane) * 16;
            int g = 0, v;
            do {
                v = __hip_atomic_load(fp, __ATOMIC_RELAXED, __HIP_MEMORY_SCOPE_AGENT);
            } while (v < t + 1 && ++g < (1 << 20));
        }

        // ---- reload own k-slice: 16 in-flight sc1 loads
        const _Float16* xb = xchg + (size_t)((t + 1) & 1) * (BATCH * DIM);
        uint4 q[16];
        #pragma unroll
        for (int i = 0; i < 16; ++i) {
            const int row = 2 * i + rl_rh;
            const _Float16* ap = xb + (size_t)row * DIM + rl_blk * 8;
            asm volatile("global_load_dwordx4 %0, %1, off sc1"
                         : "=v"(q[i]) : "v"(ap) : "memory");
        }
        // ---- outputs AFTER the reloads: excluded from the vmcnt(2) wait,
        // they retire in background during the next MFMA phase.
        __builtin_nontemporal_store(h, (f32x4*)(hs + (size_t)t * (BATCH * DIM)
                                                + (size_t)er * DIM + wcol0 + ec4));
        *(f32x4*)(slot + (size_t)er * DIM + wcol0 + ec4) = h;
        asm volatile("s_waitcnt vmcnt(2)" ::: "memory");   // 16 oldest = reloads
        __builtin_amdgcn_sched_barrier(0);
        #pragma unroll
        for (int i = 0; i < 16; ++i) {
            const int row = 2 * i + rl_rh;
            *(uint4*)&Hs[((row << 7) + (rl_blk ^ (row & 7))) * 8] = q[i];
        }
        // no barrier: next MFMA reads only this wave's own k-blocks
    }
}

extern "C" void kernel_launch(void* const* d_in, const int* in_sizes, int n_in,
                              void* d_out, int out_size, void* d_ws, size_t ws_size,
                              hipStream_t stream) {
    const float* x    = (const float*)d_in[0];   // [T][B][D]
    const float* h0   = (const float*)d_in[1];   // [B][D]
    const float* Wx   = (const float*)d_in[2];   // [D][D]
    const float* Wh   = (const float*)d_in[3];   // [D][D]
    const float* bias = (const float*)d_in[4];   // [D]

    float* hs    = (float*)d_out;
    float* h_all = hs + (size_t)T_STEPS * BATCH * DIM;

    int*       flags = (int*)d_ws;                              // 512 ints (wg flags, 64B apart)
    _Float16*  xchg  = (_Float16*)((char*)d_ws + 4096);         // 128 KB ring (2 slots)
    _Float16*  P     = (_Float16*)((char*)d_ws + 4096 + 131072);// 2 MB packed W_h

    flag_init<<<1, 1024, 0, stream>>>((int*)d_ws);
    conv_pack<<<(DIM * DIM) / 256, 256, 0, stream>>>(Wh, P);

    dim3 g((T_STEPS * BATCH) / BM, DIM / BN);
    gemm_xw<<<g, 256, 0, stream>>>(x, Wx, bias, h_all + (size_t)BATCH * DIM);

    elman_rec<<<NWG, 256, 0, stream>>>(h0, P, hs, h_all, flags, xchg);
}